// Round 5
// baseline (330.970 us; speedup 1.0000x reference)
//
#include <hip/hip_runtime.h>
#include <hip/hip_bf16.h>

typedef __hip_bfloat16 bf16;

// R5: per-buffer dtype sniffing. Evidence so far:
//  - insertion order confirmed (in_sizes[0]==2097152 branch executed, R4)
//  - all-as-bf16 read => NaN  => at least one input is f32
//  - all-as-f32 read  => finite, wrong by 3.09 with triple-verified math
//    => at least one input is bf16 (bf16-as-f32 is always finite)
//  => MIXED dtypes. Sniff each buffer: bf16 data has exponent-looking bits
//     in BOTH u16 halves of every 32-bit word; f32 data has mantissa bits in
//     the lo half (P(false bf16) ~ 2e-10 over 32 words). Zero buffers -> flag 2.
// flags[i]: 0=f32, 1=bf16, 2=all-zero. flags[13]=any bf16 (output dtype).

__device__ __forceinline__ float ldf(const void* p, int f, long idx) {
    if (f == 0) return ((const float*)p)[idx];
    if (f == 1) {
        unsigned int u = ((unsigned int)((const unsigned short*)p)[idx]) << 16;
        float r; __builtin_memcpy(&r, &u, 4); return r;
    }
    return 0.f;
}

__global__ __launch_bounds__(64) void sniff_kernel(
    const void* p0, const void* p1, const void* p2, const void* p3,
    const void* p4, const void* p5, const void* p6, const void* p7,
    const void* p8, const void* p9, const void* p10, const void* p11,
    const void* p12,
    int n0, int n1, int n2, int n3, int n4, int n5, int n6, int n7,
    int n8, int n9, int n10, int n11, int n12,
    int* flags)
{
    const void* ps[13] = {p0,p1,p2,p3,p4,p5,p6,p7,p8,p9,p10,p11,p12};
    int ns[13] = {n0,n1,n2,n3,n4,n5,n6,n7,n8,n9,n10,n11,n12};
    int i = threadIdx.x;
    if (i < 13) {
        const unsigned short* u = (const unsigned short*)ps[i];
        int n16 = ns[i] < 64 ? ns[i] : 64;   // stay within els*2 bytes (bf16-safe)
        bool allzero = true;
        for (int j = 0; j < n16; ++j) if (u[j] != 0) { allzero = false; break; }
        int flag;
        if (allzero) flag = 2;
        else {
            int npair = n16 / 2;
            bool all_bf = true;
            for (int j = 0; j < npair; ++j) {
                unsigned short lo = u[2 * j], hi = u[2 * j + 1];
                int elo = (lo >> 7) & 0xFF, ehi = (hi >> 7) & 0xFF;
                bool lo_ok = (elo >= 64 && elo <= 190) || lo == 0;
                bool hi_ok = (ehi >= 64 && ehi <= 190) || hi == 0;
                if (!(lo_ok && hi_ok)) { all_bf = false; break; }
            }
            flag = all_bf ? 1 : 0;
        }
        flags[i] = flag;
    }
    __syncthreads();
    if (i == 0) {
        int any16 = 0;
        for (int j = 0; j < 13; ++j) if (flags[j] == 1) any16 = 1;
        flags[13] = any16;
    }
}

// K1: one block (64 threads) per (b,t) row; scalar staging + scalar dots.
__global__ __launch_bounds__(64) void proj_kernel(
    const void* __restrict__ x,
    const void* __restrict__ Wk, const void* __restrict__ bk,
    const void* __restrict__ Wv, const void* __restrict__ bv,
    const void* __restrict__ Wr, const void* __restrict__ br,
    const int* __restrict__ flg,
    float* __restrict__ k_ws, float* __restrict__ v_ws, float* __restrict__ r_ws)
{
    int fx = flg[0], fWk = flg[5], fbk = flg[6], fWv = flg[7],
        fbv = flg[8], fWr = flg[9], fbr = flg[10];
    int row = blockIdx.x;
    int b = row >> 10, t = row & 1023;
    int lane = threadIdx.x;
    __shared__ float xs[512];

    for (int c = lane; c < 512; c += 64) {
        float val;
        if (c < 256) val = (t == 0) ? 0.f : ldf(x, fx, (long)(b * 1024 + (t - 1)) * 512 + c);
        else         val = ldf(x, fx, (long)(b * 1024 + t) * 512 + c);
        xs[c] = val;
    }
    __syncthreads();

    if (lane < 48) {
        int d = lane & 15;
        const void* W; int fW; float bias;
        if (lane < 16)      { W = Wk; fW = fWk; bias = ldf(bk, fbk, d); }
        else if (lane < 32) { W = Wv; fW = fWv; bias = ldf(bv, fbv, d); }
        else                { W = Wr; fW = fWr; bias = ldf(br, fbr, d); }
        float acc = 0.f;
        for (int c = 0; c < 512; ++c) acc += xs[c] * ldf(W, fW, (long)d * 512 + c);
        float p = acc + bias;
        size_t oidx = (size_t)(b * 16 + d) * 1024 + t;
        if (lane < 16)      k_ws[oidx] = expf(fminf(fmaxf(p, -60.f), 30.f));
        else if (lane < 32) v_ws[oidx] = p;
        else                r_ws[oidx] = p;
    }
}

// K2: w_sum[u] = alpha[u] * sum_{s=0..1023-u} tw[1023-s]*beta[u+s]
__global__ __launch_bounds__(64) void wsum_kernel(
    const void* __restrict__ tw, const void* __restrict__ alpha,
    const void* __restrict__ beta, const int* __restrict__ flg,
    float* __restrict__ w_sum)
{
    int ftw = flg[1], fal = flg[2], fbe = flg[3];
    int u = blockIdx.x;
    int lane = threadIdx.x;
    __shared__ float red[64];
    float acc = 0.f;
    int n = 1024 - u;
    for (int s = lane; s < n; s += 64)
        acc += ldf(tw, ftw, 1023 - s) * ldf(beta, fbe, u + s);
    red[lane] = acc;
    __syncthreads();
    for (int off = 32; off > 0; off >>= 1) {
        if (lane < off) red[lane] += red[lane + off];
        __syncthreads();
    }
    if (lane == 0) w_sum[u] = red[0] * ldf(alpha, fal, u);
}

// K3: serial scan per (b,d). <<<1,64>>>
__global__ __launch_bounds__(64) void scan_kernel(
    const float* __restrict__ k_ws, const float* __restrict__ v_ws,
    float* __restrict__ cumk, float* __restrict__ kvmean)
{
    int bd = threadIdx.x;
    size_t base = (size_t)bd * 1024;
    float run = 0.f, kvsum = 0.f;
    for (int t = 0; t < 1024; ++t) {
        float kk = k_ws[base + t];
        run += kk;
        cumk[base + t] = run;
        kvsum += kk * v_ws[base + t];
    }
    kvmean[bd] = kvsum * (1.0f / 1024.0f);
}

// K4: one thread per (b,t,o); output dtype chosen by flags[13].
__global__ __launch_bounds__(256) void out_kernel(
    const float* __restrict__ r_ws, const float* __restrict__ cumk,
    const float* __restrict__ kvmean, const float* __restrict__ w_sum,
    const void* __restrict__ Wo, const void* __restrict__ bo,
    const void* __restrict__ gamma, const int* __restrict__ flg,
    void* __restrict__ out)
{
    int fWo = flg[11], fbo = flg[12], fga = flg[4], any16 = flg[13];
    int g = blockIdx.x * 256 + threadIdx.x;   // [0, 262144)
    int o = g & 63;
    int row = g >> 6;
    int b = row >> 10, t = row & 1023;
    float ws_t = w_sum[t];
    float acc = 0.f;
    for (int d = 0; d < 16; ++d) {
        size_t idx = (size_t)(b * 16 + d) * 1024 + t;
        float rwkv = r_ws[idx] * ws_t * kvmean[b * 16 + d] / (cumk[idx] + 1e-8f);
        acc += ldf(Wo, fWo, o * 16 + d) * rwkv;
    }
    float val = (acc + ldf(bo, fbo, o)) * ldf(gamma, fga, t);
    if (any16) ((bf16*)out)[g] = __float2bfloat16(val);
    else       ((float*)out)[g] = val;
}

extern "C" void kernel_launch(void* const* d_in, const int* in_sizes, int n_in,
                              void* d_out, int out_size, void* d_ws, size_t ws_size,
                              hipStream_t stream) {
    // insertion order (confirmed): x, time_w, time_alpha, time_beta, time_gamma,
    //                              Wk, bk, Wv, bv, Wr, br, Wo, bo
    const void* x     = d_in[0];
    const void* tw    = d_in[1];
    const void* alpha = d_in[2];
    const void* beta  = d_in[3];
    const void* gamma = d_in[4];
    const void* Wk    = d_in[5];
    const void* bk    = d_in[6];
    const void* Wv    = d_in[7];
    const void* bv    = d_in[8];
    const void* Wr    = d_in[9];
    const void* br    = d_in[10];
    const void* Wo    = d_in[11];
    const void* bo    = d_in[12];

    float* ws     = (float*)d_ws;
    float* k_ws   = ws;             // 65536
    float* v_ws   = ws + 65536;     // 65536
    float* r_ws   = ws + 131072;    // 65536
    float* cumk   = ws + 196608;    // 65536
    float* kvmean = ws + 262144;    // 64
    float* w_sum  = ws + 262208;    // 1024
    int*   flags  = (int*)(ws + 263232);  // 16 ints

    sniff_kernel<<<1, 64, 0, stream>>>(
        x, tw, alpha, beta, gamma, Wk, bk, Wv, bv, Wr, br, Wo, bo,
        in_sizes[0], in_sizes[1], in_sizes[2], in_sizes[3], in_sizes[4],
        in_sizes[5], in_sizes[6], in_sizes[7], in_sizes[8], in_sizes[9],
        in_sizes[10], in_sizes[11], in_sizes[12],
        flags);
    proj_kernel<<<4096, 64, 0, stream>>>(x, Wk, bk, Wv, bv, Wr, br, flags,
                                         k_ws, v_ws, r_ws);
    wsum_kernel<<<1024, 64, 0, stream>>>(tw, alpha, beta, flags, w_sum);
    scan_kernel<<<1, 64, 0, stream>>>(k_ws, v_ws, cumk, kvmean);
    out_kernel<<<1024, 256, 0, stream>>>(r_ws, cumk, kvmean, w_sum,
                                         Wo, bo, gamma, flags, (void*)d_out);
}

// Round 6
// 147.791 us; speedup vs baseline: 2.2394x; 2.2394x over previous
//
#include <hip/hip_runtime.h>
#include <hip/hip_bf16.h>

typedef __hip_bfloat16 bf16;

// R6: same verified math + dtype sniffing as R5 (PASSED, absmax 4.9e-4).
// Perf rewrite:
//  - prep kernel normalizes W{k,v,r}+biases into transposed padded f32 WT[c][64]
//    -> proj's weight reads are 256B coalesced and flag-free
//  - proj: dtype branch hoisted out of staging; 4-chain unrolled dot
//  - k/v/r/cumk stored [t][bd] (bd=b*16+d) -> scan & out read coalesced
//  - scan: single 1024-thread block, segmented (64 serial + 16-seg LDS pass),
//    cumk in place over k_ws (same-thread read-then-write only)

__device__ __forceinline__ float ldf(const void* p, int f, long idx) {
    if (f == 0) return ((const float*)p)[idx];
    if (f == 1) {
        unsigned int u = ((unsigned int)((const unsigned short*)p)[idx]) << 16;
        float r; __builtin_memcpy(&r, &u, 4); return r;
    }
    return 0.f;
}

// flags[i]: 0=f32, 1=bf16, 2=all-zero. flags[13] = any bf16 (output dtype).
__global__ __launch_bounds__(64) void sniff_kernel(
    const void* p0, const void* p1, const void* p2, const void* p3,
    const void* p4, const void* p5, const void* p6, const void* p7,
    const void* p8, const void* p9, const void* p10, const void* p11,
    const void* p12,
    int n0, int n1, int n2, int n3, int n4, int n5, int n6, int n7,
    int n8, int n9, int n10, int n11, int n12,
    int* flags)
{
    const void* ps[13] = {p0,p1,p2,p3,p4,p5,p6,p7,p8,p9,p10,p11,p12};
    int ns[13] = {n0,n1,n2,n3,n4,n5,n6,n7,n8,n9,n10,n11,n12};
    int i = threadIdx.x;
    if (i < 13) {
        const unsigned short* u = (const unsigned short*)ps[i];
        int n16 = ns[i] < 64 ? ns[i] : 64;
        bool allzero = true;
        for (int j = 0; j < n16; ++j) if (u[j] != 0) { allzero = false; break; }
        int flag;
        if (allzero) flag = 2;
        else {
            int npair = n16 / 2;
            bool all_bf = true;
            for (int j = 0; j < npair; ++j) {
                unsigned short lo = u[2 * j], hi = u[2 * j + 1];
                int elo = (lo >> 7) & 0xFF, ehi = (hi >> 7) & 0xFF;
                bool lo_ok = (elo >= 64 && elo <= 190) || lo == 0;
                bool hi_ok = (ehi >= 64 && ehi <= 190) || hi == 0;
                if (!(lo_ok && hi_ok)) { all_bf = false; break; }
            }
            flag = all_bf ? 1 : 0;
        }
        flags[i] = flag;
    }
    __syncthreads();
    if (i == 0) {
        int any16 = 0;
        for (int j = 0; j < 13; ++j) if (flags[j] == 1) any16 = 1;
        flags[13] = any16;
    }
}

// prep: WT[c*64+o] = W_sel[d][c] (f32, zero-padded o>=48); biasWS[o].
__global__ __launch_bounds__(256) void prep_kernel(
    const void* Wk, const void* bk, const void* Wv, const void* bv,
    const void* Wr, const void* br, const int* __restrict__ flg,
    float* __restrict__ WT, float* __restrict__ biasWS)
{
    int idx = blockIdx.x * 256 + threadIdx.x;   // 32768 = 512*64
    int c = idx >> 6, o = idx & 63;
    float val = 0.f;
    if (o < 16)      val = ldf(Wk, flg[5], (long)o * 512 + c);
    else if (o < 32) val = ldf(Wv, flg[7], (long)(o - 16) * 512 + c);
    else if (o < 48) val = ldf(Wr, flg[9], (long)(o - 32) * 512 + c);
    WT[idx] = val;
    if (idx < 64) {
        float bb = 0.f;
        if (idx < 16)      bb = ldf(bk, flg[6], idx);
        else if (idx < 32) bb = ldf(bv, flg[8], idx - 16);
        else if (idx < 48) bb = ldf(br, flg[10], idx - 32);
        biasWS[idx] = bb;
    }
}

// proj: one wave per (b,t) row; lane o in [0,48) -> k/v/r, layout [t][bd].
__global__ __launch_bounds__(64) void proj_kernel(
    const void* __restrict__ x, const float* __restrict__ WT,
    const float* __restrict__ biasWS, const int* __restrict__ flg,
    float* __restrict__ k_ws, float* __restrict__ v_ws, float* __restrict__ r_ws)
{
    int row = blockIdx.x;
    int b = row >> 10, t = row & 1023;
    int lane = threadIdx.x;
    __shared__ float xs[512];
    int fx = flg[0];

    if (fx == 1) {
        const unsigned short* xp = (const unsigned short*)x;
        #pragma unroll
        for (int j = 0; j < 8; ++j) {
            int c = lane + 64 * j;
            int ts = (c < 256) ? t - 1 : t;
            float v = 0.f;
            if (ts >= 0) {
                unsigned int u = ((unsigned int)xp[(long)(b * 1024 + ts) * 512 + c]) << 16;
                __builtin_memcpy(&v, &u, 4);
            }
            xs[c] = v;
        }
    } else {
        const float* xp = (const float*)x;
        #pragma unroll
        for (int j = 0; j < 8; ++j) {
            int c = lane + 64 * j;
            int ts = (c < 256) ? t - 1 : t;
            xs[c] = (ts >= 0) ? xp[(long)(b * 1024 + ts) * 512 + c] : 0.f;
        }
    }
    __syncthreads();

    int o = lane;
    const float* Wp = WT + o;
    float a0 = 0.f, a1 = 0.f, a2 = 0.f, a3 = 0.f;
    #pragma unroll 8
    for (int c = 0; c < 512; c += 4) {
        a0 += xs[c + 0] * Wp[(c + 0) * 64];
        a1 += xs[c + 1] * Wp[(c + 1) * 64];
        a2 += xs[c + 2] * Wp[(c + 2) * 64];
        a3 += xs[c + 3] * Wp[(c + 3) * 64];
    }
    float p = (a0 + a1) + (a2 + a3) + biasWS[o];
    if (o < 48) {
        int d = o & 15;
        long oidx = (long)t * 64 + b * 16 + d;
        if (o < 16)      k_ws[oidx] = expf(fminf(fmaxf(p, -60.f), 30.f));
        else if (o < 32) v_ws[oidx] = p;
        else             r_ws[oidx] = p;
    }
}

// wsum: w_sum[u] = alpha[u] * sum_{s=0..1023-u} tw[1023-s]*beta[u+s]  (as R5)
__global__ __launch_bounds__(64) void wsum_kernel(
    const void* __restrict__ tw, const void* __restrict__ alpha,
    const void* __restrict__ beta, const int* __restrict__ flg,
    float* __restrict__ w_sum)
{
    int ftw = flg[1], fal = flg[2], fbe = flg[3];
    int u = blockIdx.x;
    int lane = threadIdx.x;
    __shared__ float red[64];
    float acc = 0.f;
    int n = 1024 - u;
    for (int s = lane; s < n; s += 64)
        acc += ldf(tw, ftw, 1023 - s) * ldf(beta, fbe, u + s);
    red[lane] = acc;
    __syncthreads();
    for (int off = 32; off > 0; off >>= 1) {
        if (lane < off) red[lane] += red[lane + off];
        __syncthreads();
    }
    if (lane == 0) w_sum[u] = red[0] * ldf(alpha, fal, u);
}

// scan: one 1024-thread block. tid=(seg,bd); 16 segs x 64 t's. cumk in place.
__global__ __launch_bounds__(1024) void scan_kernel(
    float* k_ws, const float* __restrict__ v_ws, float* __restrict__ kvmean)
{
    int tid = threadIdx.x;
    int bd = tid & 63, seg = tid >> 6;
    __shared__ float sums[16][64];
    __shared__ float kvs[16][64];
    int t0 = seg * 64;
    float part = 0.f, kvp = 0.f;
    for (int i = 0; i < 64; ++i) {
        long a = (long)(t0 + i) * 64 + bd;
        float kk = k_ws[a];
        part += kk;
        kvp += kk * v_ws[a];
    }
    sums[seg][bd] = part;
    kvs[seg][bd] = kvp;
    __syncthreads();
    if (tid < 64) {
        float base = 0.f, kvt = 0.f;
        for (int s = 0; s < 16; ++s) {
            float tmp = sums[s][tid];
            sums[s][tid] = base;       // exclusive segment base
            base += tmp;
            kvt += kvs[s][tid];
        }
        kvmean[tid] = kvt * (1.0f / 1024.0f);
    }
    __syncthreads();
    float run = sums[seg][bd];
    for (int i = 0; i < 64; ++i) {
        long a = (long)(t0 + i) * 64 + bd;
        float kk = k_ws[a];
        run += kk;
        k_ws[a] = run;                 // in-place cumk (same-thread RAW only)
    }
}

// out: thread per (b,t,o); [t][bd] layout reads are broadcast/coalesced.
__global__ __launch_bounds__(256) void out_kernel(
    const float* __restrict__ r_ws, const float* __restrict__ cumk,
    const float* __restrict__ kvmean, const float* __restrict__ w_sum,
    const void* __restrict__ Wo, const void* __restrict__ bo,
    const void* __restrict__ gamma, const int* __restrict__ flg,
    void* __restrict__ out)
{
    int fWo = flg[11], fbo = flg[12], fga = flg[4], any16 = flg[13];
    int g = blockIdx.x * 256 + threadIdx.x;   // [0, 262144)
    int o = g & 63;
    int row = g >> 6;
    int b = row >> 10, t = row & 1023;
    float ws_t = w_sum[t];
    float acc = 0.f;
    #pragma unroll
    for (int d = 0; d < 16; ++d) {
        long a = (long)t * 64 + b * 16 + d;
        float rwkv = r_ws[a] * ws_t * kvmean[b * 16 + d] / (cumk[a] + 1e-8f);
        acc += ldf(Wo, fWo, o * 16 + d) * rwkv;
    }
    float val = (acc + ldf(bo, fbo, o)) * ldf(gamma, fga, t);
    if (any16) ((bf16*)out)[g] = __float2bfloat16(val);
    else       ((float*)out)[g] = val;
}

extern "C" void kernel_launch(void* const* d_in, const int* in_sizes, int n_in,
                              void* d_out, int out_size, void* d_ws, size_t ws_size,
                              hipStream_t stream) {
    // insertion order (confirmed R4): x, time_w, time_alpha, time_beta,
    // time_gamma, Wk, bk, Wv, bv, Wr, br, Wo, bo
    const void* x     = d_in[0];
    const void* tw    = d_in[1];
    const void* alpha = d_in[2];
    const void* beta  = d_in[3];
    const void* gamma = d_in[4];
    const void* Wk    = d_in[5];
    const void* bk    = d_in[6];
    const void* Wv    = d_in[7];
    const void* bv    = d_in[8];
    const void* Wr    = d_in[9];
    const void* br    = d_in[10];
    const void* Wo    = d_in[11];
    const void* bo    = d_in[12];

    float* ws     = (float*)d_ws;
    float* k_ws   = ws;             // 65536  ([t][bd]; becomes cumk in place)
    float* v_ws   = ws + 65536;     // 65536
    float* r_ws   = ws + 131072;    // 65536
    float* WT     = ws + 196608;    // 32768  (512 x 64 padded)
    float* biasWS = ws + 229376;    // 64
    float* kvmean = ws + 229440;    // 64
    float* w_sum  = ws + 229504;    // 1024
    int*   flags  = (int*)(ws + 230528);  // 16 ints  (total ~922 KB < R5's 1.05MB)

    sniff_kernel<<<1, 64, 0, stream>>>(
        x, tw, alpha, beta, gamma, Wk, bk, Wv, bv, Wr, br, Wo, bo,
        in_sizes[0], in_sizes[1], in_sizes[2], in_sizes[3], in_sizes[4],
        in_sizes[5], in_sizes[6], in_sizes[7], in_sizes[8], in_sizes[9],
        in_sizes[10], in_sizes[11], in_sizes[12],
        flags);
    prep_kernel<<<128, 256, 0, stream>>>(Wk, bk, Wv, bv, Wr, br, flags,
                                         WT, biasWS);
    proj_kernel<<<4096, 64, 0, stream>>>(x, WT, biasWS, flags,
                                         k_ws, v_ws, r_ws);
    wsum_kernel<<<1024, 64, 0, stream>>>(tw, alpha, beta, flags, w_sum);
    scan_kernel<<<1, 1024, 0, stream>>>(k_ws, v_ws, kvmean);
    out_kernel<<<1024, 256, 0, stream>>>(r_ws, k_ws, kvmean, w_sum,
                                         Wo, bo, gamma, flags, (void*)d_out);
}

// Round 7
// 123.624 us; speedup vs baseline: 2.6772x; 1.1955x over previous
//
#include <hip/hip_runtime.h>
#include <hip/hip_bf16.h>

typedef __hip_bfloat16 bf16;

// R7: perf round on the verified R5/R6 math + dtype-sniff structure.
//  - proj: 16 rows/block register tiling, float4-interleaved W (WT4), LDS x-tile
//  - scan: split into 2 grid-parallel kernels (16 CUs instead of 1)
//  - prep: normalizes Wo/bo/gamma to f32 too (flag-free hot loops)
// flags[i]: 0=f32, 1=bf16, 2=all-zero. flags[13] = any bf16 (output dtype).

__device__ __forceinline__ float ldf(const void* p, int f, long idx) {
    if (f == 0) return ((const float*)p)[idx];
    if (f == 1) {
        unsigned int u = ((unsigned int)((const unsigned short*)p)[idx]) << 16;
        float r; __builtin_memcpy(&r, &u, 4); return r;
    }
    return 0.f;
}

__global__ __launch_bounds__(64) void sniff_kernel(
    const void* p0, const void* p1, const void* p2, const void* p3,
    const void* p4, const void* p5, const void* p6, const void* p7,
    const void* p8, const void* p9, const void* p10, const void* p11,
    const void* p12,
    int n0, int n1, int n2, int n3, int n4, int n5, int n6, int n7,
    int n8, int n9, int n10, int n11, int n12,
    int* flags)
{
    const void* ps[13] = {p0,p1,p2,p3,p4,p5,p6,p7,p8,p9,p10,p11,p12};
    int ns[13] = {n0,n1,n2,n3,n4,n5,n6,n7,n8,n9,n10,n11,n12};
    int i = threadIdx.x;
    if (i < 13) {
        const unsigned short* u = (const unsigned short*)ps[i];
        int n16 = ns[i] < 64 ? ns[i] : 64;
        bool allzero = true;
        for (int j = 0; j < n16; ++j) if (u[j] != 0) { allzero = false; break; }
        int flag;
        if (allzero) flag = 2;
        else {
            int npair = n16 / 2;
            bool all_bf = true;
            for (int j = 0; j < npair; ++j) {
                unsigned short lo = u[2 * j], hi = u[2 * j + 1];
                int elo = (lo >> 7) & 0xFF, ehi = (hi >> 7) & 0xFF;
                bool lo_ok = (elo >= 64 && elo <= 190) || lo == 0;
                bool hi_ok = (ehi >= 64 && ehi <= 190) || hi == 0;
                if (!(lo_ok && hi_ok)) { all_bf = false; break; }
            }
            flag = all_bf ? 1 : 0;
        }
        flags[i] = flag;
    }
    __syncthreads();
    if (i == 0) {
        int any16 = 0;
        for (int j = 0; j < 13; ++j) if (flags[j] == 1) any16 = 1;
        flags[13] = any16;
    }
}

// prep: WT4[(c/4)*256 + o*4 + c%4] = W_sel[d][c] (f32, zero-pad o>=48);
// plus biasWS[64], WoF[1024], gammaF[1024], boF[64].
__global__ __launch_bounds__(256) void prep_kernel(
    const void* Wk, const void* bk, const void* Wv, const void* bv,
    const void* Wr, const void* br, const void* Wo, const void* bo,
    const void* gamma, const int* __restrict__ flg,
    float* __restrict__ WT4, float* __restrict__ biasWS,
    float* __restrict__ WoF, float* __restrict__ boF, float* __restrict__ gammaF)
{
    int idx = blockIdx.x * 256 + threadIdx.x;
    if (idx < 32768) {
        int q = idx >> 8, rem = idx & 255;
        int o = rem >> 2, c = q * 4 + (rem & 3);
        float val = 0.f;
        if (o < 16)      val = ldf(Wk, flg[5], (long)o * 512 + c);
        else if (o < 32) val = ldf(Wv, flg[7], (long)(o - 16) * 512 + c);
        else if (o < 48) val = ldf(Wr, flg[9], (long)(o - 32) * 512 + c);
        WT4[idx] = val;
    } else if (idx < 33792) {
        int i = idx - 32768;
        WoF[i] = ldf(Wo, flg[11], i);
    } else if (idx < 34816) {
        int i = idx - 33792;
        gammaF[i] = ldf(gamma, flg[4], i);
    } else if (idx < 34880) {
        int i = idx - 34816;
        boF[i] = ldf(bo, flg[12], i);
    } else if (idx < 34944) {
        int i = idx - 34880;
        float bb = 0.f;
        if (i < 16)      bb = ldf(bk, flg[6], i);
        else if (i < 32) bb = ldf(bv, flg[8], i - 16);
        else if (i < 48) bb = ldf(br, flg[10], i - 32);
        biasWS[i] = bb;
    }
}

// proj: 16 rows/block, 256 threads = 64 o x 4 c-chunks. [t][bd] outputs.
__global__ __launch_bounds__(256) void proj_kernel(
    const void* __restrict__ x, const float* __restrict__ WT4,
    const float* __restrict__ biasWS, const int* __restrict__ flg,
    float* __restrict__ k_ws, float* __restrict__ v_ws, float* __restrict__ r_ws)
{
    __shared__ float xs[16 * 512];      // 32 KB
    __shared__ float red[4 * 16 * 64];  // 16 KB
    int tid = threadIdx.x;
    int row0 = blockIdx.x * 16;         // global row base
    int b = row0 >> 10;
    int lt0 = row0 & 1023;              // local t base (16-aligned, same b)
    int fx = flg[0];

    // stage 16 rows x 512 ch, float4 per thread-iteration; first 256 ch from t-1
    if (fx == 1) {
        const unsigned short* xp = (const unsigned short*)x;
        #pragma unroll
        for (int j = 0; j < 8; ++j) {
            int v = tid + 256 * j;            // float4 id, < 2048
            int el = v * 4;
            int r = el >> 9, c = el & 511;
            int lt = lt0 + r - ((c < 256) ? 1 : 0);
            float4 f;
            if (lt < 0) f = make_float4(0.f, 0.f, 0.f, 0.f);
            else {
                const unsigned short* sp = xp + ((long)(b * 1024 + lt) * 512 + c);
                unsigned int u0 = ((unsigned int)sp[0]) << 16;
                unsigned int u1 = ((unsigned int)sp[1]) << 16;
                unsigned int u2 = ((unsigned int)sp[2]) << 16;
                unsigned int u3 = ((unsigned int)sp[3]) << 16;
                __builtin_memcpy(&f.x, &u0, 4); __builtin_memcpy(&f.y, &u1, 4);
                __builtin_memcpy(&f.z, &u2, 4); __builtin_memcpy(&f.w, &u3, 4);
            }
            reinterpret_cast<float4*>(xs)[v] = f;
        }
    } else {
        const float* xp = (const float*)x;
        #pragma unroll
        for (int j = 0; j < 8; ++j) {
            int v = tid + 256 * j;
            int el = v * 4;
            int r = el >> 9, c = el & 511;
            int lt = lt0 + r - ((c < 256) ? 1 : 0);
            float4 f;
            if (lt < 0) f = make_float4(0.f, 0.f, 0.f, 0.f);
            else f = *reinterpret_cast<const float4*>(xp + ((long)(b * 1024 + lt) * 512 + c));
            reinterpret_cast<float4*>(xs)[v] = f;
        }
    }
    __syncthreads();

    int o = tid & 63, cc = tid >> 6;
    const float4* xs4 = reinterpret_cast<const float4*>(xs);
    const float4* W4 = reinterpret_cast<const float4*>(WT4);
    float acc[16];
    #pragma unroll
    for (int r = 0; r < 16; ++r) acc[r] = 0.f;
    int qbase = cc * 32;                 // 32 c-quads = 128 channels per chunk
    for (int q = 0; q < 32; ++q) {
        int cq = qbase + q;
        float4 w4 = W4[cq * 64 + o];     // coalesced 1KB/wave
        #pragma unroll
        for (int r = 0; r < 16; ++r) {
            float4 x4 = xs4[r * 128 + cq];   // wave-broadcast LDS read
            acc[r] += x4.x * w4.x + x4.y * w4.y + x4.z * w4.z + x4.w * w4.w;
        }
    }
    #pragma unroll
    for (int r = 0; r < 16; ++r)
        red[(cc * 16 + r) * 64 + o] = acc[r];
    __syncthreads();

    #pragma unroll
    for (int it = 0; it < 4; ++it) {
        int idx = tid + 256 * it;        // < 1024
        int o2 = idx & 63, r2 = idx >> 6;
        float s = red[(0 * 16 + r2) * 64 + o2] + red[(1 * 16 + r2) * 64 + o2]
                + red[(2 * 16 + r2) * 64 + o2] + red[(3 * 16 + r2) * 64 + o2]
                + biasWS[o2];
        if (o2 < 48) {
            int d = o2 & 15;
            long a = (long)(lt0 + r2) * 64 + b * 16 + d;
            if (o2 < 16)      k_ws[a] = expf(fminf(fmaxf(s, -60.f), 30.f));
            else if (o2 < 32) v_ws[a] = s;
            else              r_ws[a] = s;
        }
    }
}

// wsum: w_sum[u] = alpha[u] * sum_{s=0..1023-u} tw[1023-s]*beta[u+s]
__global__ __launch_bounds__(64) void wsum_kernel(
    const void* __restrict__ tw, const void* __restrict__ alpha,
    const void* __restrict__ beta, const int* __restrict__ flg,
    float* __restrict__ w_sum)
{
    int ftw = flg[1], fal = flg[2], fbe = flg[3];
    int u = blockIdx.x;
    int lane = threadIdx.x;
    __shared__ float red[64];
    float acc = 0.f;
    int n = 1024 - u;
    for (int s = lane; s < n; s += 64)
        acc += ldf(tw, ftw, 1023 - s) * ldf(beta, fbe, u + s);
    red[lane] = acc;
    __syncthreads();
    for (int off = 32; off > 0; off >>= 1) {
        if (lane < off) red[lane] += red[lane + off];
        __syncthreads();
    }
    if (lane == 0) w_sum[u] = red[0] * ldf(alpha, fal, u);
}

// scanA: per-(seg,bd) partial sums of k and k*v. 16 blocks x 64.
__global__ __launch_bounds__(64) void scanA_kernel(
    const float* __restrict__ k_ws, const float* __restrict__ v_ws,
    float* __restrict__ segsum, float* __restrict__ segkv)
{
    int seg = blockIdx.x, bd = threadIdx.x;
    float part = 0.f, kvp = 0.f;
    for (int i = 0; i < 64; ++i) {
        long a = (long)(seg * 64 + i) * 64 + bd;
        float kk = k_ws[a];
        part += kk;
        kvp += kk * v_ws[a];
    }
    segsum[seg * 64 + bd] = part;
    segkv[seg * 64 + bd] = kvp;
}

// scanB: add exclusive base, write cumk in place; block 0 writes kvmean.
__global__ __launch_bounds__(64) void scanB_kernel(
    float* k_ws, const float* __restrict__ segsum,
    const float* __restrict__ segkv, float* __restrict__ kvmean)
{
    int seg = blockIdx.x, bd = threadIdx.x;
    float run = 0.f;
    for (int s = 0; s < seg; ++s) run += segsum[s * 64 + bd];
    for (int i = 0; i < 64; ++i) {
        long a = (long)(seg * 64 + i) * 64 + bd;
        run += k_ws[a];
        k_ws[a] = run;            // in-place cumk (same-thread RAW only)
    }
    if (seg == 0) {
        float kvt = 0.f;
        for (int s = 0; s < 16; ++s) kvt += segkv[s * 64 + bd];
        kvmean[bd] = kvt * (1.0f / 1024.0f);
    }
}

// out: 4 rows/block; rwkv[16] per row via LDS, float4 Wo dots. Flag-free
// except output dtype.
__global__ __launch_bounds__(256) void out_kernel(
    const float* __restrict__ r_ws, const float* __restrict__ cumk,
    const float* __restrict__ kvmean, const float* __restrict__ w_sum,
    const float* __restrict__ WoF, const float* __restrict__ boF,
    const float* __restrict__ gammaF, const int* __restrict__ flg,
    void* __restrict__ out)
{
    int tid = threadIdx.x;
    int rl = tid >> 6, o = tid & 63;
    int row = blockIdx.x * 4 + rl;
    int b = row >> 10, t = row & 1023;
    __shared__ float rw[4][16];
    if (o < 16) {
        long a = (long)t * 64 + b * 16 + o;
        rw[rl][o] = r_ws[a] * w_sum[t] * kvmean[b * 16 + o] / (cumk[a] + 1e-8f);
    }
    __syncthreads();
    float acc = boF[o];
    const float4* W4 = reinterpret_cast<const float4*>(WoF + o * 16);
    #pragma unroll
    for (int j = 0; j < 4; ++j) {
        float4 w = W4[j];
        acc += rw[rl][4 * j + 0] * w.x + rw[rl][4 * j + 1] * w.y +
               rw[rl][4 * j + 2] * w.z + rw[rl][4 * j + 3] * w.w;
    }
    float val = acc * gammaF[t];
    if (flg[13]) ((bf16*)out)[(long)row * 64 + o] = __float2bfloat16(val);
    else         ((float*)out)[(long)row * 64 + o] = val;
}

extern "C" void kernel_launch(void* const* d_in, const int* in_sizes, int n_in,
                              void* d_out, int out_size, void* d_ws, size_t ws_size,
                              hipStream_t stream) {
    // insertion order (confirmed R4): x, time_w, time_alpha, time_beta,
    // time_gamma, Wk, bk, Wv, bv, Wr, br, Wo, bo
    const void* x     = d_in[0];
    const void* tw    = d_in[1];
    const void* alpha = d_in[2];
    const void* beta  = d_in[3];
    const void* gamma = d_in[4];
    const void* Wk    = d_in[5];
    const void* bk    = d_in[6];
    const void* Wv    = d_in[7];
    const void* bv    = d_in[8];
    const void* Wr    = d_in[9];
    const void* br    = d_in[10];
    const void* Wo    = d_in[11];
    const void* bo    = d_in[12];

    float* ws     = (float*)d_ws;
    float* k_ws   = ws;             // 65536  [t][bd]; becomes cumk in place
    float* v_ws   = ws + 65536;     // 65536
    float* r_ws   = ws + 131072;    // 65536
    float* WT4    = ws + 196608;    // 32768  (c/4-major, o*4 interleave)
    float* biasWS = ws + 229376;    // 64
    float* WoF    = ws + 229440;    // 1024
    float* boF    = ws + 230464;    // 64
    float* gammaF = ws + 230528;    // 1024
    float* kvmean = ws + 231552;    // 64
    float* w_sum  = ws + 231616;    // 1024
    float* segsum = ws + 232640;    // 1024
    float* segkv  = ws + 233664;    // 1024
    int*   flags  = (int*)(ws + 234688);  // 16 ints

    sniff_kernel<<<1, 64, 0, stream>>>(
        x, tw, alpha, beta, gamma, Wk, bk, Wv, bv, Wr, br, Wo, bo,
        in_sizes[0], in_sizes[1], in_sizes[2], in_sizes[3], in_sizes[4],
        in_sizes[5], in_sizes[6], in_sizes[7], in_sizes[8], in_sizes[9],
        in_sizes[10], in_sizes[11], in_sizes[12],
        flags);
    prep_kernel<<<137, 256, 0, stream>>>(Wk, bk, Wv, bv, Wr, br, Wo, bo,
                                         gamma, flags,
                                         WT4, biasWS, WoF, boF, gammaF);
    proj_kernel<<<256, 256, 0, stream>>>(x, WT4, biasWS, flags,
                                         k_ws, v_ws, r_ws);
    wsum_kernel<<<1024, 64, 0, stream>>>(tw, alpha, beta, flags, w_sum);
    scanA_kernel<<<16, 64, 0, stream>>>(k_ws, v_ws, segsum, segkv);
    scanB_kernel<<<16, 64, 0, stream>>>(k_ws, segsum, segkv, kvmean);
    out_kernel<<<1024, 256, 0, stream>>>(r_ws, k_ws, kvmean, w_sum,
                                         WoF, boF, gammaF, flags, (void*)d_out);
}

// Round 8
// 114.297 us; speedup vs baseline: 2.8957x; 1.0816x over previous
//
#include <hip/hip_runtime.h>
#include <hip/hip_bf16.h>

typedef __hip_bfloat16 bf16;

// R8: verified R5-R7 math + dtype sniffing; dispatch-count and proj-LDS round.
//  - setup_kernel = sniff + prep + wsum fused (1024 blocks; per-block local
//    sniff into LDS, block 0 publishes global flags for proj/out)
//  - proj: 8 rows/block, 4 outputs/thread -> 64 ds_read_b128/wave (was 512)
//  - scanA/scanB/out unchanged (already small)
// flags[i]: 0=f32, 1=bf16, 2=all-zero. flags[13] = any bf16 (output dtype).

__device__ __forceinline__ float ldf(const void* p, int f, long idx) {
    if (f == 0) return ((const float*)p)[idx];
    if (f == 1) {
        unsigned int u = ((unsigned int)((const unsigned short*)p)[idx]) << 16;
        float r; __builtin_memcpy(&r, &u, 4); return r;
    }
    return 0.f;
}

__device__ __forceinline__ int sniff_one(const unsigned short* u, int els) {
    int n16 = els < 64 ? els : 64;
    bool allzero = true;
    for (int j = 0; j < n16; ++j) if (u[j] != 0) { allzero = false; break; }
    if (allzero) return 2;
    int npair = n16 / 2;
    for (int j = 0; j < npair; ++j) {
        unsigned short lo = u[2 * j], hi = u[2 * j + 1];
        int elo = (lo >> 7) & 0xFF, ehi = (hi >> 7) & 0xFF;
        bool lo_ok = (elo >= 64 && elo <= 190) || lo == 0;
        bool hi_ok = (ehi >= 64 && ehi <= 190) || hi == 0;
        if (!(lo_ok && hi_ok)) return 0;
    }
    return 1;
}

// setup: grid 1024 x 256.
//  every block : local sniff (threads 0..12) -> LDS flags
//  block 0     : publish flags[0..13] to global (for proj/out)
//  blocks 0-136: prep chunk (WT4 / WoF / gammaF / boF / biasWS)
//  every block : wsum for u = blockIdx.x
__global__ __launch_bounds__(256) void setup_kernel(
    const void* x, const void* tw, const void* alpha, const void* beta,
    const void* gamma, const void* Wk, const void* bk, const void* Wv,
    const void* bv, const void* Wr, const void* br, const void* Wo,
    const void* bo,
    int n0, int n1, int n2, int n3, int n4, int n5, int n6, int n7,
    int n8, int n9, int n10, int n11, int n12,
    int* __restrict__ flags,
    float* __restrict__ WT4, float* __restrict__ biasWS,
    float* __restrict__ WoF, float* __restrict__ boF,
    float* __restrict__ gammaF, float* __restrict__ w_sum)
{
    __shared__ int sf[16];
    __shared__ float red[256];
    int tid = threadIdx.x;
    const void* ps[13] = {x,tw,alpha,beta,gamma,Wk,bk,Wv,bv,Wr,br,Wo,bo};
    int ns[13] = {n0,n1,n2,n3,n4,n5,n6,n7,n8,n9,n10,n11,n12};
    if (tid < 13) sf[tid] = sniff_one((const unsigned short*)ps[tid], ns[tid]);
    __syncthreads();
    if (tid == 0) {
        int any16 = 0;
        for (int j = 0; j < 13; ++j) if (sf[j] == 1) any16 = 1;
        sf[13] = any16;
    }
    __syncthreads();
    if (blockIdx.x == 0 && tid < 14) flags[tid] = sf[tid];

    // ---- prep chunk ----
    int idx = blockIdx.x * 256 + tid;
    if (idx < 32768) {
        int q = idx >> 8, rem = idx & 255;
        int o = rem >> 2, c = q * 4 + (rem & 3);
        float val = 0.f;
        if (o < 16)      val = ldf(Wk, sf[5], (long)o * 512 + c);
        else if (o < 32) val = ldf(Wv, sf[7], (long)(o - 16) * 512 + c);
        else if (o < 48) val = ldf(Wr, sf[9], (long)(o - 32) * 512 + c);
        WT4[idx] = val;
    } else if (idx < 33792) {
        int i = idx - 32768;
        WoF[i] = ldf(Wo, sf[11], i);
    } else if (idx < 34816) {
        int i = idx - 33792;
        gammaF[i] = ldf(gamma, sf[4], i);
    } else if (idx < 34880) {
        int i = idx - 34816;
        boF[i] = ldf(bo, sf[12], i);
    } else if (idx < 34944) {
        int i = idx - 34880;
        float bb = 0.f;
        if (i < 16)      bb = ldf(bk, sf[6], i);
        else if (i < 32) bb = ldf(bv, sf[8], i - 16);
        else if (i < 48) bb = ldf(br, sf[10], i - 32);
        biasWS[i] = bb;
    }

    // ---- wsum for u = blockIdx.x ----
    int u = blockIdx.x;
    int ftw = sf[1], fal = sf[2], fbe = sf[3];
    float acc = 0.f;
    int n = 1024 - u;
    for (int s = tid; s < n; s += 256)
        acc += ldf(tw, ftw, 1023 - s) * ldf(beta, fbe, u + s);
    red[tid] = acc;
    __syncthreads();
    for (int off = 128; off > 0; off >>= 1) {
        if (tid < off) red[tid] += red[tid + off];
        __syncthreads();
    }
    if (tid == 0) w_sum[u] = red[0] * ldf(alpha, fal, u);
}

// proj: 8 rows/block (grid 512), 256 threads = 16 o-quads x 16 c-chunks.
// Each thread: 4 outputs x 8 rows; x4 LDS read feeds 16 FMA.
__global__ __launch_bounds__(256) void proj_kernel(
    const void* __restrict__ x, const float* __restrict__ WT4,
    const float* __restrict__ biasWS, const int* __restrict__ flg,
    float* __restrict__ k_ws, float* __restrict__ v_ws, float* __restrict__ r_ws)
{
    __shared__ float xs[8 * 512];       // 16 KB
    __shared__ float red[16 * 8 * 64];  // 32 KB
    int tid = threadIdx.x;
    int row0 = blockIdx.x * 8;
    int b = row0 >> 10;
    int lt0 = row0 & 1023;
    int fx = flg[0];

    // stage 8 rows x 512 ch (1024 float4); first 256 ch from t-1
    if (fx == 1) {
        const unsigned short* xp = (const unsigned short*)x;
        #pragma unroll
        for (int j = 0; j < 4; ++j) {
            int v = tid + 256 * j;
            int el = v * 4;
            int r = el >> 9, c = el & 511;
            int lt = lt0 + r - ((c < 256) ? 1 : 0);
            float4 f;
            if (lt < 0) f = make_float4(0.f, 0.f, 0.f, 0.f);
            else {
                const unsigned short* sp = xp + ((long)(b * 1024 + lt) * 512 + c);
                unsigned int u0 = ((unsigned int)sp[0]) << 16;
                unsigned int u1 = ((unsigned int)sp[1]) << 16;
                unsigned int u2 = ((unsigned int)sp[2]) << 16;
                unsigned int u3 = ((unsigned int)sp[3]) << 16;
                __builtin_memcpy(&f.x, &u0, 4); __builtin_memcpy(&f.y, &u1, 4);
                __builtin_memcpy(&f.z, &u2, 4); __builtin_memcpy(&f.w, &u3, 4);
            }
            reinterpret_cast<float4*>(xs)[v] = f;
        }
    } else {
        const float* xp = (const float*)x;
        #pragma unroll
        for (int j = 0; j < 4; ++j) {
            int v = tid + 256 * j;
            int el = v * 4;
            int r = el >> 9, c = el & 511;
            int lt = lt0 + r - ((c < 256) ? 1 : 0);
            float4 f;
            if (lt < 0) f = make_float4(0.f, 0.f, 0.f, 0.f);
            else f = *reinterpret_cast<const float4*>(xp + ((long)(b * 1024 + lt) * 512 + c));
            reinterpret_cast<float4*>(xs)[v] = f;
        }
    }
    __syncthreads();

    int o4 = tid & 15, cc = tid >> 4;   // o = o4*4+j ; cc chunk = 32 channels
    const float4* xs4 = reinterpret_cast<const float4*>(xs);
    const float4* W4 = reinterpret_cast<const float4*>(WT4);
    float a0[8], a1[8], a2[8], a3[8];
    #pragma unroll
    for (int r = 0; r < 8; ++r) { a0[r] = a1[r] = a2[r] = a3[r] = 0.f; }
    #pragma unroll
    for (int q = 0; q < 8; ++q) {
        int cq = cc * 8 + q;
        float4 w0 = W4[cq * 64 + o4 * 4 + 0];
        float4 w1 = W4[cq * 64 + o4 * 4 + 1];
        float4 w2 = W4[cq * 64 + o4 * 4 + 2];
        float4 w3 = W4[cq * 64 + o4 * 4 + 3];
        #pragma unroll
        for (int r = 0; r < 8; ++r) {
            float4 x4 = xs4[r * 128 + cq];
            a0[r] += x4.x * w0.x + x4.y * w0.y + x4.z * w0.z + x4.w * w0.w;
            a1[r] += x4.x * w1.x + x4.y * w1.y + x4.z * w1.z + x4.w * w1.w;
            a2[r] += x4.x * w2.x + x4.y * w2.y + x4.z * w2.z + x4.w * w2.w;
            a3[r] += x4.x * w3.x + x4.y * w3.y + x4.z * w3.z + x4.w * w3.w;
        }
    }
    float4* red4 = reinterpret_cast<float4*>(red);
    #pragma unroll
    for (int r = 0; r < 8; ++r)
        red4[(cc * 8 + r) * 16 + o4] = make_float4(a0[r], a1[r], a2[r], a3[r]);
    __syncthreads();

    #pragma unroll
    for (int it = 0; it < 2; ++it) {
        int idx = tid + 256 * it;        // < 512
        int o2 = idx & 63, r2 = idx >> 6;
        float s = biasWS[o2];
        #pragma unroll
        for (int cc2 = 0; cc2 < 16; ++cc2)
            s += red[(cc2 * 8 + r2) * 64 + o2];
        if (o2 < 48) {
            int d = o2 & 15;
            long a = (long)(lt0 + r2) * 64 + b * 16 + d;
            if (o2 < 16)      k_ws[a] = expf(fminf(fmaxf(s, -60.f), 30.f));
            else if (o2 < 32) v_ws[a] = s;
            else              r_ws[a] = s;
        }
    }
}

// scanA: per-(seg,bd) partial sums of k and k*v. 16 blocks x 64.
__global__ __launch_bounds__(64) void scanA_kernel(
    const float* __restrict__ k_ws, const float* __restrict__ v_ws,
    float* __restrict__ segsum, float* __restrict__ segkv)
{
    int seg = blockIdx.x, bd = threadIdx.x;
    float part = 0.f, kvp = 0.f;
    for (int i = 0; i < 64; ++i) {
        long a = (long)(seg * 64 + i) * 64 + bd;
        float kk = k_ws[a];
        part += kk;
        kvp += kk * v_ws[a];
    }
    segsum[seg * 64 + bd] = part;
    segkv[seg * 64 + bd] = kvp;
}

// scanB: add exclusive base, write cumk in place; block 0 writes kvmean.
__global__ __launch_bounds__(64) void scanB_kernel(
    float* k_ws, const float* __restrict__ segsum,
    const float* __restrict__ segkv, float* __restrict__ kvmean)
{
    int seg = blockIdx.x, bd = threadIdx.x;
    float run = 0.f;
    for (int s = 0; s < seg; ++s) run += segsum[s * 64 + bd];
    for (int i = 0; i < 64; ++i) {
        long a = (long)(seg * 64 + i) * 64 + bd;
        run += k_ws[a];
        k_ws[a] = run;            // in-place cumk (same-thread RAW only)
    }
    if (seg == 0) {
        float kvt = 0.f;
        for (int s = 0; s < 16; ++s) kvt += segkv[s * 64 + bd];
        kvmean[bd] = kvt * (1.0f / 1024.0f);
    }
}

// out: 4 rows/block; rwkv[16] per row via LDS, float4 Wo dots.
__global__ __launch_bounds__(256) void out_kernel(
    const float* __restrict__ r_ws, const float* __restrict__ cumk,
    const float* __restrict__ kvmean, const float* __restrict__ w_sum,
    const float* __restrict__ WoF, const float* __restrict__ boF,
    const float* __restrict__ gammaF, const int* __restrict__ flg,
    void* __restrict__ out)
{
    int tid = threadIdx.x;
    int rl = tid >> 6, o = tid & 63;
    int row = blockIdx.x * 4 + rl;
    int b = row >> 10, t = row & 1023;
    __shared__ float rw[4][16];
    if (o < 16) {
        long a = (long)t * 64 + b * 16 + o;
        rw[rl][o] = r_ws[a] * w_sum[t] * kvmean[b * 16 + o] / (cumk[a] + 1e-8f);
    }
    __syncthreads();
    float acc = boF[o];
    const float4* W4 = reinterpret_cast<const float4*>(WoF + o * 16);
    #pragma unroll
    for (int j = 0; j < 4; ++j) {
        float4 w = W4[j];
        acc += rw[rl][4 * j + 0] * w.x + rw[rl][4 * j + 1] * w.y +
               rw[rl][4 * j + 2] * w.z + rw[rl][4 * j + 3] * w.w;
    }
    float val = acc * gammaF[t];
    if (flg[13]) ((bf16*)out)[(long)row * 64 + o] = __float2bfloat16(val);
    else         ((float*)out)[(long)row * 64 + o] = val;
}

extern "C" void kernel_launch(void* const* d_in, const int* in_sizes, int n_in,
                              void* d_out, int out_size, void* d_ws, size_t ws_size,
                              hipStream_t stream) {
    // insertion order (confirmed R4): x, time_w, time_alpha, time_beta,
    // time_gamma, Wk, bk, Wv, bv, Wr, br, Wo, bo
    const void* x     = d_in[0];
    const void* tw    = d_in[1];
    const void* alpha = d_in[2];
    const void* beta  = d_in[3];
    const void* gamma = d_in[4];
    const void* Wk    = d_in[5];
    const void* bk    = d_in[6];
    const void* Wv    = d_in[7];
    const void* bv    = d_in[8];
    const void* Wr    = d_in[9];
    const void* br    = d_in[10];
    const void* Wo    = d_in[11];
    const void* bo    = d_in[12];

    float* ws     = (float*)d_ws;
    float* k_ws   = ws;             // 65536  [t][bd]; becomes cumk in place
    float* v_ws   = ws + 65536;     // 65536
    float* r_ws   = ws + 131072;    // 65536
    float* WT4    = ws + 196608;    // 32768
    float* biasWS = ws + 229376;    // 64
    float* WoF    = ws + 229440;    // 1024
    float* boF    = ws + 230464;    // 64
    float* gammaF = ws + 230528;    // 1024
    float* kvmean = ws + 231552;    // 64
    float* w_sum  = ws + 231616;    // 1024
    float* segsum = ws + 232640;    // 1024
    float* segkv  = ws + 233664;    // 1024
    int*   flags  = (int*)(ws + 234688);  // 16 ints

    setup_kernel<<<1024, 256, 0, stream>>>(
        x, tw, alpha, beta, gamma, Wk, bk, Wv, bv, Wr, br, Wo, bo,
        in_sizes[0], in_sizes[1], in_sizes[2], in_sizes[3], in_sizes[4],
        in_sizes[5], in_sizes[6], in_sizes[7], in_sizes[8], in_sizes[9],
        in_sizes[10], in_sizes[11], in_sizes[12],
        flags, WT4, biasWS, WoF, boF, gammaF, w_sum);
    proj_kernel<<<512, 256, 0, stream>>>(x, WT4, biasWS, flags,
                                         k_ws, v_ws, r_ws);
    scanA_kernel<<<16, 64, 0, stream>>>(k_ws, v_ws, segsum, segkv);
    scanB_kernel<<<16, 64, 0, stream>>>(k_ws, segsum, segkv, kvmean);
    out_kernel<<<1024, 256, 0, stream>>>(r_ws, k_ws, kvmean, w_sum,
                                         WoF, boF, gammaF, flags, (void*)d_out);
}